// Round 21
// baseline (291.187 us; speedup 1.0000x reference)
//
#include <hip/hip_runtime.h>
#include <math.h>

#define Bn 8
#define Cn 112
#define Hn 64
#define Wn 64
#define On 112
#define Gn 14
#define PGC 378          // 3*G*K2
#define HW 4096          // 64*64
#define CKW 1008         // C*K2
#define KP 1024          // padded K (main GEMM and dense pg GEMM)
#define NP 384           // padded N (oc) for pg GEMM
#define XROW 4356        // 66*66 rows per batch
#define PG_MT 137        // M-tiles of 256
#define MPAD (PG_MT * 256)                 // 35072
#define PLANE_ROWS 34848                   // 8 batches * 4356 rows per plane
#define XGUARD 67
#define XTG_ROWS_TOTAL 558080              // padded alloc rows

typedef __attribute__((ext_vector_type(8))) short bf16x8;
typedef __attribute__((ext_vector_type(4))) float f32x4;

__device__ __forceinline__ unsigned short f2bf(float f) {
    union { float f; unsigned int u; } v; v.f = f;
    unsigned int r = v.u + 0x7fffu + ((v.u >> 16) & 1u);
    return (unsigned short)(r >> 16);
}
__device__ __forceinline__ float bf2f(unsigned short u) {
    union { unsigned int u; float f; } v; v.u = ((unsigned int)u) << 16;
    return v.f;
}
__device__ __forceinline__ float bflo(unsigned int u) {
    union { unsigned int u; float f; } v; v.u = u << 16; return v.f;
}
__device__ __forceinline__ float bfhi(unsigned int u) {
    union { unsigned int u; float f; } v; v.u = u & 0xffff0000u; return v.f;
}
__device__ __forceinline__ void gload_lds16(const void* g, void* l) {
    __builtin_amdgcn_global_load_lds(
        (const __attribute__((address_space(1))) unsigned int*)g,
        (__attribute__((address_space(3))) unsigned int*)l, 16, 0, 0);
}

// ---------------------------------------------------------------------------
// prep (merged): zero XTG alloc | B2 dense [384][1024] | WB [128][1024]
// ---------------------------------------------------------------------------
#define ZN XTG_ROWS_TOTAL
#define B2N (NP * KP)
#define WBN (128 * KP)
__global__ __launch_bounds__(256) void prep_kernel(
    const float* __restrict__ pgw, const float* __restrict__ w,
    unsigned short* __restrict__ XTGa, unsigned short* __restrict__ B2,
    unsigned short* __restrict__ WB)
{
    int t = blockIdx.x * 256 + threadIdx.x;
    if (t < ZN) {
        const uint4 z = {0, 0, 0, 0};
        reinterpret_cast<uint4*>(XTGa)[t] = z;
        return;
    }
    t -= ZN;
    if (t < B2N) {
        int oc = t >> 10, ck = t & 1023;
        int pg_ = ck >> 3, cc = ck & 7;
        int tap = pg_ / 14, pl = pg_ % 14;
        float v = (pg_ < 126 && oc < PGC)
            ? pgw[(size_t)oc * CKW + (pl * 8 + cc) * 9 + tap] : 0.f;
        B2[t] = f2bf(v);
        return;
    }
    t -= B2N;
    if (t < WBN) {
        int oc = t >> 10, ck = t & 1023;
        float v = 0.f;
        if (oc < On && ck < CKW) {
            int g = ck / 72, r = ck % 72;
            int k = r >> 3, cc = r & 7;
            v = w[(size_t)oc * CKW + (g * 8 + cc) * 9 + k];
        }
        WB[t] = f2bf(v);
    }
}

// ---------------------------------------------------------------------------
// xpose: x NCHW f32 -> XTG bf16 planes [g][b][row66x66][8ch]
// ---------------------------------------------------------------------------
__global__ __launch_bounds__(256) void xpose_kernel(
    const float* __restrict__ x, unsigned short* __restrict__ XTG)
{
    __shared__ unsigned short lds[64][136];

    const int tid = threadIdx.x;
    const int y = blockIdx.x, b = blockIdx.y;
    const int xx = tid & 63, cw = tid >> 6;

    const float* xb = x + (size_t)b * Cn * HW + y * 64;
    #pragma unroll
    for (int p = 0; p < 28; ++p) {
        int c = p * 4 + cw;
        lds[xx][c] = f2bf(xb[(size_t)c * HW + xx]);
    }
    __syncthreads();

    #pragma unroll
    for (int q = 0; q < 4; ++q) {
        int task = q * 256 + tid;
        if (task < 896) {
            int g = task >> 6;
            int x2 = task & 63;
            unsigned short* dst = XTG + ((size_t)g * PLANE_ROWS
                + (size_t)b * XROW + (y + 1) * 66 + x2 + 1) * 8;
            *reinterpret_cast<uint4*>(dst) =
                *reinterpret_cast<const uint4*>(&lds[x2][g * 8]);
        }
    }
}

// ---------------------------------------------------------------------------
// pg shift-GEMM v9: dense-K (1024), BK=32, 256x128 tile, 8 waves, per-wave
// 64x64.  TWO LDS buffers (48 KB) -> 3 blocks/CU, ALL 411 blocks co-resident
// (24 waves/CU: inter-block stall hiding, m114).  2-barrier dbuf schedule
// with counted vmcnt(3); swizzle v8 (chunk ^= (row>>1)&3).
// Epilogue: two 64-oc passes through a 33.8 KB LDS transpose.
// ---------------------------------------------------------------------------
#define A_BUF_B 16384
#define B_BUF_B 8192
__global__ __launch_bounds__(512, 6) void pg_shift_kernel(
    const unsigned short* __restrict__ XTG, const unsigned short* __restrict__ B2,
    const float* __restrict__ pgb, unsigned short* __restrict__ pgBF)
{
    __shared__ __align__(16) unsigned char smem[2 * (A_BUF_B + B_BUF_B)]; // 48 KB

    const int tid  = threadIdx.x;
    const int lane = tid & 63;
    const int w    = tid >> 6;
    const int wr   = w >> 1;
    const int wc   = w & 1;
    const int m0   = blockIdx.x * 256;
    const int n0   = blockIdx.y * 128;
    const int fr   = lane & 15, fq = lane >> 4;

    f32x4 acc[4][4] = {};

    auto Abuf = [&](int b) -> unsigned char* { return smem + b * A_BUF_B; };
    auto Bbuf = [&](int b) -> unsigned char* {
        return smem + 2 * A_BUF_B + b * B_BUF_B; };

    auto stage = [&](int buf, int kt) {
        #pragma unroll
        for (int s = 0; s < 2; ++s) {
            int r = w * 32 + s * 16 + (lane >> 2);
            int ch = (lane & 3) ^ ((r >> 1) & 3);
            int pg_ = kt * 4 + ch;
            int tap = pg_ / 14, pl = pg_ % 14;
            int shift = (tap / 3 - 1) * 66 + (tap % 3) - 1;
            if (pg_ >= 126) { pl = 14; shift = 0; }
            gload_lds16(XTG + ((long)pl * PLANE_ROWS + (long)(m0 + r) + shift) * 8,
                        Abuf(buf) + (w * 32 + s * 16) * 64);
        }
        {
            int r = w * 16 + (lane >> 2);
            int ch = (lane & 3) ^ ((r >> 1) & 3);
            gload_lds16(&B2[(size_t)(n0 + r) * KP + kt * 32 + ch * 8],
                        Bbuf(buf) + (w * 16) * 64);
        }
    };

    stage(0, 0);
    int cur = 0;
    for (int kt = 0; kt < 32; ++kt) {
        if (kt + 1 < 32) {
            stage(cur ^ 1, kt + 1);
            asm volatile("s_waitcnt vmcnt(3)" ::: "memory");
        } else {
            asm volatile("s_waitcnt vmcnt(0)" ::: "memory");
        }
        __builtin_amdgcn_s_barrier();
        asm volatile("" ::: "memory");

        const unsigned char* Ab = Abuf(cur);
        const unsigned char* Bb = Bbuf(cur);

        bf16x8 a[4], b[4];
        #pragma unroll
        for (int mi = 0; mi < 4; ++mi) {
            int r = wr * 64 + mi * 16 + fr;
            a[mi] = *reinterpret_cast<const bf16x8*>(
                Ab + r * 64 + ((fq ^ ((r >> 1) & 3)) << 4));
        }
        #pragma unroll
        for (int ni = 0; ni < 4; ++ni) {
            int r = wc * 64 + ni * 16 + fr;
            b[ni] = *reinterpret_cast<const bf16x8*>(
                Bb + r * 64 + ((fq ^ ((r >> 1) & 3)) << 4));
        }

        __builtin_amdgcn_s_setprio(1);
        #pragma unroll
        for (int mi = 0; mi < 4; ++mi)
            #pragma unroll
            for (int ni = 0; ni < 4; ++ni)
                acc[mi][ni] = __builtin_amdgcn_mfma_f32_16x16x32_bf16(
                    a[mi], b[ni], acc[mi][ni], 0, 0, 0);
        __builtin_amdgcn_s_setprio(0);

        asm volatile("s_waitcnt lgkmcnt(0)" ::: "memory");
        __builtin_amdgcn_s_barrier();
        asm volatile("" ::: "memory");
        cur ^= 1;
    }

    // ---------------- epilogue: two-pass LDS transpose + coalesced store --
    unsigned short* T = (unsigned short*)smem;   // [64 oc][264 px] = 33.8 KB

    const int pxls = tid & 255;
    const int ho   = tid >> 8;                   // wave-uniform (0/1)
    const int pxd  = m0 + pxls;
    const int bb   = pxd / XROW;
    const int rem  = pxd - bb * XROW;
    const int yy   = rem / 66 - 1;
    const int xx   = rem - (yy + 1) * 66 - 1;
    const bool valid = (pxd < Bn * XROW) &&
                       ((unsigned)yy < 64u) && ((unsigned)xx < 64u);
    unsigned short* pbase = pgBF + (size_t)bb * PGC * HW + yy * 64 + xx;

    #pragma unroll
    for (int h = 0; h < 2; ++h) {
        if (wc == h) {
            #pragma unroll
            for (int ni = 0; ni < 4; ++ni) {
                int ocl = ni * 16 + fr;               // 0..63 within half
                int ocg = n0 + h * 64 + ocl;
                float bv = (ocg < PGC) ? pgb[ocg] : 0.f;
                #pragma unroll
                for (int mi = 0; mi < 4; ++mi) {
                    int pxl = wr * 64 + mi * 16 + fq * 4;
                    ushort4 pk;
                    pk.x = f2bf(acc[mi][ni][0] + bv);
                    pk.y = f2bf(acc[mi][ni][1] + bv);
                    pk.z = f2bf(acc[mi][ni][2] + bv);
                    pk.w = f2bf(acc[mi][ni][3] + bv);
                    *reinterpret_cast<ushort4*>(&T[ocl * 264 + pxl]) = pk;
                }
            }
        }
        __builtin_amdgcn_s_barrier();
        #pragma unroll 4
        for (int j = 0; j < 32; ++j) {
            int ocg = n0 + h * 64 + ho * 32 + j;      // wave-uniform
            if (ocg < PGC) {
                unsigned short v = T[(ho * 32 + j) * 264 + pxls];
                if (valid) pbase[(size_t)ocg * HW] = v;
            }
        }
        if (h == 0) {
            __builtin_amdgcn_s_barrier();             // before overwriting T
        }
    }
}

// ---------------------------------------------------------------------------
// fused sample+GEMM v2 (validated round 20): block = 32 px, BK=64, 16 tiles,
// one tap-task per thread, 40 KB LDS -> 4 blocks/CU, XCD-affine grid.
// ---------------------------------------------------------------------------
__global__ __launch_bounds__(256, 4) void fused_kernel(
    const unsigned short* __restrict__ XTG, const unsigned short* __restrict__ pg,
    const unsigned short* __restrict__ WB, const float* __restrict__ bias,
    float* __restrict__ out)
{
    __shared__ __align__(16) unsigned char Ab[2][32 * 128];   //  8 KB
    __shared__ __align__(16) unsigned char Bb[2][128 * 128];  // 32 KB

    const int tid  = threadIdx.x;
    const int lane = tid & 63;
    const int w    = tid >> 6;
    const int fr   = lane & 15, fq = lane >> 4;

    const int bid = (int)blockIdx.x;
    const int blk = (bid & 7) * 128 + (bid >> 3);
    const int px0 = blk * 32;
    const int b   = px0 >> 12;
    const int hw0 = px0 & 4095;

    const int spx = tid & 31;
    const int q   = tid >> 5;
    const int hw  = hw0 + spx;
    const int sy  = hw >> 6, sx = hw & 63;

    const unsigned short* pgb = pg + (size_t)b * PGC * HW + hw;

    f32x4 acc[2][2] = {};

    unsigned short rdy, rdx, rmv;
    float fdy, fdx, fmv;
    uint4 q00, q01, q10, q11;
    float w00, w01, w10, w11;

    auto issue_pg = [&](int kt) {
        int gk = kt * 8 + q;
        int gkc = min(gk, 125);
        int g = gkc / 9, k = gkc - 9 * g;
        rdy = pgb[(size_t)(18 * g + 2 * k) * HW];
        rdx = pgb[(size_t)(18 * g + 2 * k + 1) * HW];
        rmv = pgb[(size_t)(252 + 9 * g + k) * HW];
    };

    auto issue_gather = [&](int kt1) {
        int gk = kt1 * 8 + q;
        bool valid = gk < 126;
        int gkc = min(gk, 125);
        int g = gkc / 9, k = gkc - 9 * g;
        const int ky = k / 3, kx = k - 3 * ky;
        float m = valid ? 1.f / (1.f + __expf(-fmv)) : 0.f;
        float yf = (float)(sy + ky - 1) + fdy;
        float xf = (float)(sx + kx - 1) + fdx;
        float y0 = floorf(yf), x0 = floorf(xf);
        float wy1 = yf - y0, wx1 = xf - x0;
        float wy0 = 1.f - wy1, wx0 = 1.f - wx1;
        int iy0 = (int)y0, ix0 = (int)x0;
        bool vy0 = (iy0 >= 0) && (iy0 < Hn);
        bool vy1 = (iy0 >= -1) && (iy0 < Hn - 1);
        bool vx0 = (ix0 >= 0) && (ix0 < Wn);
        bool vx1 = (ix0 >= -1) && (ix0 < Wn - 1);
        int cy0 = min(max(iy0, 0), Hn - 1), cy1 = min(max(iy0 + 1, 0), Hn - 1);
        int cx0 = min(max(ix0, 0), Wn - 1), cx1 = min(max(ix0 + 1, 0), Wn - 1);
        w00 = (vy0 && vx0) ? wy0 * wx0 * m : 0.f;
        w01 = (vy0 && vx1) ? wy0 * wx1 * m : 0.f;
        w10 = (vy1 && vx0) ? wy1 * wx0 * m : 0.f;
        w11 = (vy1 && vx1) ? wy1 * wx1 * m : 0.f;
        const unsigned short* xg = XTG +
            ((size_t)g * PLANE_ROWS + (size_t)b * XROW) * 8;
        q00 = *reinterpret_cast<const uint4*>(xg + (size_t)((cy0 + 1) * 66 + cx0 + 1) * 8);
        q01 = *reinterpret_cast<const uint4*>(xg + (size_t)((cy0 + 1) * 66 + cx1 + 1) * 8);
        q10 = *reinterpret_cast<const uint4*>(xg + (size_t)((cy1 + 1) * 66 + cx0 + 1) * 8);
        q11 = *reinterpret_cast<const uint4*>(xg + (size_t)((cy1 + 1) * 66 + cx1 + 1) * 8);
    };

    auto combine_write = [&](int buf) {
        unsigned int c00[4] = {q00.x, q00.y, q00.z, q00.w};
        unsigned int c01[4] = {q01.x, q01.y, q01.z, q01.w};
        unsigned int c10[4] = {q10.x, q10.y, q10.z, q10.w};
        unsigned int c11[4] = {q11.x, q11.y, q11.z, q11.w};
        unsigned int pk[4];
        #pragma unroll
        for (int j = 0; j < 4; ++j) {
            float lo = bflo(c00[j]) * w00 + bflo(c01[j]) * w01 +
                       bflo(c10[j]) * w10 + bflo(c11[j]) * w11;
            float hi = bfhi(c00[j]) * w00 + bfhi(c01[j]) * w01 +
                       bfhi(c10[j]) * w10 + bfhi(c11[j]) * w11;
            pk[j] = (unsigned int)f2bf(lo) | ((unsigned int)f2bf(hi) << 16);
        }
        int slot = q ^ (spx & 7);
        *reinterpret_cast<uint4*>(Ab[buf] + spx * 128 + slot * 16) =
            *reinterpret_cast<const uint4*>(pk);
    };

    auto stageB = [&](int buf, int kt) {
        #pragma unroll
        for (int s = 0; s < 4; ++s) {
            int r = s * 32 + w * 8 + (lane >> 3);
            int ch = (lane & 7) ^ (r & 7);
            gload_lds16(&WB[(size_t)r * KP + kt * 64 + ch * 8],
                        Bb[buf] + (s * 32 + w * 8) * 128);
        }
    };

    auto mfma_tile = [&](int c) {
        #pragma unroll
        for (int ks = 0; ks < 2; ++ks) {
            bf16x8 a[2], bfr[2];
            #pragma unroll
            for (int mi = 0; mi < 2; ++mi) {
                int r = mi * 16 + fr;
                a[mi] = *reinterpret_cast<const bf16x8*>(
                    Ab[c] + r * 128 + (((ks * 4 + fq) ^ (r & 7)) << 4));
            }
            #pragma unroll
            for (int ni = 0; ni < 2; ++ni) {
                int r = w * 32 + ni * 16 + fr;
                bfr[ni] = *reinterpret_cast<const bf16x8*>(
                    Bb[c] + r * 128 + (((ks * 4 + fq) ^ (r & 7)) << 4));
            }
            __builtin_amdgcn_s_setprio(1);
            #pragma unroll
            for (int mi = 0; mi < 2; ++mi)
                #pragma unroll
                for (int ni = 0; ni < 2; ++ni)
                    acc[mi][ni] = __builtin_amdgcn_mfma_f32_16x16x32_bf16(
                        a[mi], bfr[ni], acc[mi][ni], 0, 0, 0);
            __builtin_amdgcn_s_setprio(0);
        }
    };

    issue_pg(0);
    asm volatile("s_waitcnt vmcnt(0)" ::: "memory");
    fdy = bf2f(rdy); fdx = bf2f(rdx); fmv = bf2f(rmv);
    issue_gather(0);
    asm volatile("" ::: "memory");
    stageB(0, 0);
    asm volatile("" ::: "memory");
    issue_pg(1);
    asm volatile("s_waitcnt vmcnt(7)" ::: "memory");
    combine_write(0);
    asm volatile("s_waitcnt vmcnt(0)" ::: "memory");
    fdy = bf2f(rdy); fdx = bf2f(rdx); fmv = bf2f(rmv);
    asm volatile("s_waitcnt lgkmcnt(0)" ::: "memory");
    __builtin_amdgcn_s_barrier();
    asm volatile("" ::: "memory");

    int cur = 0;
    for (int kt = 0; kt < 16; ++kt) {
        if (kt < 15) {
            issue_gather(kt + 1);
            asm volatile("" ::: "memory");
            stageB(cur ^ 1, kt + 1);
            asm volatile("" ::: "memory");
            issue_pg(min(kt + 2, 15));
            asm volatile("" ::: "memory");
        }
        mfma_tile(cur);
        if (kt < 15) {
            asm volatile("s_waitcnt vmcnt(7)" ::: "memory");
            combine_write(cur ^ 1);
            asm volatile("s_waitcnt vmcnt(0)" ::: "memory");
            fdy = bf2f(rdy); fdx = bf2f(rdx); fmv = bf2f(rmv);
            asm volatile("s_waitcnt lgkmcnt(0)" ::: "memory");
            __builtin_amdgcn_s_barrier();
            asm volatile("" ::: "memory");
            cur ^= 1;
        }
    }

    #pragma unroll
    for (int ni = 0; ni < 2; ++ni) {
        int oc = w * 32 + ni * 16 + fr;
        if (oc >= On) continue;
        float bv = bias[oc];
        #pragma unroll
        for (int mi = 0; mi < 2; ++mi) {
            int hwo = hw0 + mi * 16 + fq * 4;
            float4 o;
            o.x = acc[mi][ni][0] + bv;
            o.y = acc[mi][ni][1] + bv;
            o.z = acc[mi][ni][2] + bv;
            o.w = acc[mi][ni][3] + bv;
            *reinterpret_cast<float4*>(
                &out[((size_t)(b * On + oc)) * HW + hwo]) = o;
        }
    }
}

// ---------------------------------------------------------------------------
extern "C" void kernel_launch(void* const* d_in, const int* in_sizes, int n_in,
                              void* d_out, int out_size, void* d_ws, size_t ws_size,
                              hipStream_t stream) {
    const float* x    = (const float*)d_in[0];
    const float* pgw  = (const float*)d_in[1];
    const float* pgb  = (const float*)d_in[2];
    const float* w    = (const float*)d_in[3];
    const float* bias = (const float*)d_in[4];
    float* out = (float*)d_out;

    char* wsb = (char*)d_ws;
    unsigned short* pgBF = (unsigned short*)wsb;                 // 24.77 MB
    size_t off = (size_t)PGC * Bn * HW * 2;
    unsigned short* B2   = (unsigned short*)(wsb + off);         // 0.79 MB
    off += (size_t)NP * KP * 2;
    unsigned short* WB   = (unsigned short*)(wsb + off);         // 0.26 MB
    off += (size_t)128 * KP * 2;
    unsigned short* XTGa = (unsigned short*)(wsb + off);         // 8.93 MB
    unsigned short* XTG  = XTGa + (size_t)XGUARD * 8;            // guarded base

    // prep: zero XTG + build B2 (dense) + WB
    {
        int tot = ZN + B2N + WBN;
        prep_kernel<<<(tot + 255) / 256, 256, 0, stream>>>(pgw, w, XTGa, B2, WB);
    }
    // transpose x -> XTG (group-planar NHWC bf16, 66x66 halo)
    xpose_kernel<<<dim3(Hn, Bn), 256, 0, stream>>>(x, XTG);

    // pg conv: dense-K 256x128/BK=32, 48 KB LDS, 3 blocks/CU, all-resident
    pg_shift_kernel<<<dim3(PG_MT, NP / 128), 512, 0, stream>>>(
        XTG, B2, pgb, pgBF);

    // fused deformable sampling + main GEMM (32-px blocks, 16 waves/CU)
    fused_kernel<<<dim3(1024), 256, 0, stream>>>(XTG, pgBF, WB, bias, out);
}

// Round 22
// 91.982 us; speedup vs baseline: 3.1657x; 3.1657x over previous
//
#include <hip/hip_runtime.h>
#include <math.h>

#define Bn 8
#define Cn 112
#define Hn 64
#define Wn 64
#define On 112
#define Gn 14
#define PGC 378          // 3*G*K2
#define HW 4096          // 64*64
#define CKW 1008         // C*K2
#define KP 1024          // padded K (main GEMM and dense pg GEMM)
#define NP 384           // padded N (oc) for pg GEMM
#define XROW 4356        // 66*66 rows per batch
#define PG_MT 137        // M-tiles of 256
#define MPAD (PG_MT * 256)                 // 35072
#define PLANE_ROWS 34848                   // 8 batches * 4356 rows per plane
#define XGUARD 67
#define XTG_ROWS_TOTAL 558080              // padded alloc rows

typedef __attribute__((ext_vector_type(8))) short bf16x8;
typedef __attribute__((ext_vector_type(4))) float f32x4;

__device__ __forceinline__ unsigned short f2bf(float f) {
    union { float f; unsigned int u; } v; v.f = f;
    unsigned int r = v.u + 0x7fffu + ((v.u >> 16) & 1u);
    return (unsigned short)(r >> 16);
}
__device__ __forceinline__ float bf2f(unsigned short u) {
    union { unsigned int u; float f; } v; v.u = ((unsigned int)u) << 16;
    return v.f;
}
__device__ __forceinline__ float bflo(unsigned int u) {
    union { unsigned int u; float f; } v; v.u = u << 16; return v.f;
}
__device__ __forceinline__ float bfhi(unsigned int u) {
    union { unsigned int u; float f; } v; v.u = u & 0xffff0000u; return v.f;
}
__device__ __forceinline__ void gload_lds16(const void* g, void* l) {
    __builtin_amdgcn_global_load_lds(
        (const __attribute__((address_space(1))) unsigned int*)g,
        (__attribute__((address_space(3))) unsigned int*)l, 16, 0, 0);
}

// ---------------------------------------------------------------------------
// prep (merged): zero XTG alloc | B2 dense [384][1024] | WB [128][1024]
// ---------------------------------------------------------------------------
#define ZN XTG_ROWS_TOTAL
#define B2N (NP * KP)
#define WBN (128 * KP)
__global__ __launch_bounds__(256) void prep_kernel(
    const float* __restrict__ pgw, const float* __restrict__ w,
    unsigned short* __restrict__ XTGa, unsigned short* __restrict__ B2,
    unsigned short* __restrict__ WB)
{
    int t = blockIdx.x * 256 + threadIdx.x;
    if (t < ZN) {
        const uint4 z = {0, 0, 0, 0};
        reinterpret_cast<uint4*>(XTGa)[t] = z;
        return;
    }
    t -= ZN;
    if (t < B2N) {
        int oc = t >> 10, ck = t & 1023;
        int pg_ = ck >> 3, cc = ck & 7;
        int tap = pg_ / 14, pl = pg_ % 14;
        float v = (pg_ < 126 && oc < PGC)
            ? pgw[(size_t)oc * CKW + (pl * 8 + cc) * 9 + tap] : 0.f;
        B2[t] = f2bf(v);
        return;
    }
    t -= B2N;
    if (t < WBN) {
        int oc = t >> 10, ck = t & 1023;
        float v = 0.f;
        if (oc < On && ck < CKW) {
            int g = ck / 72, r = ck % 72;
            int k = r >> 3, cc = r & 7;
            v = w[(size_t)oc * CKW + (g * 8 + cc) * 9 + k];
        }
        WB[t] = f2bf(v);
    }
}

// ---------------------------------------------------------------------------
// xpose: x NCHW f32 -> XTG bf16 planes [g][b][row66x66][8ch]
// ---------------------------------------------------------------------------
__global__ __launch_bounds__(256) void xpose_kernel(
    const float* __restrict__ x, unsigned short* __restrict__ XTG)
{
    __shared__ unsigned short lds[64][136];

    const int tid = threadIdx.x;
    const int y = blockIdx.x, b = blockIdx.y;
    const int xx = tid & 63, cw = tid >> 6;

    const float* xb = x + (size_t)b * Cn * HW + y * 64;
    #pragma unroll
    for (int p = 0; p < 28; ++p) {
        int c = p * 4 + cw;
        lds[xx][c] = f2bf(xb[(size_t)c * HW + xx]);
    }
    __syncthreads();

    #pragma unroll
    for (int q = 0; q < 4; ++q) {
        int task = q * 256 + tid;
        if (task < 896) {
            int g = task >> 6;
            int x2 = task & 63;
            unsigned short* dst = XTG + ((size_t)g * PLANE_ROWS
                + (size_t)b * XROW + (y + 1) * 66 + x2 + 1) * 8;
            *reinterpret_cast<uint4*>(dst) =
                *reinterpret_cast<const uint4*>(&lds[x2][g * 8]);
        }
    }
}

// ---------------------------------------------------------------------------
// pg shift-GEMM v8 (round 18 exact: 3 buffers, 72 KB, (512,4), ~49 us)
// ---------------------------------------------------------------------------
#define A_BUF_B 16384
#define B_BUF_B 8192
__global__ __launch_bounds__(512, 4) void pg_shift_kernel(
    const unsigned short* __restrict__ XTG, const unsigned short* __restrict__ B2,
    const float* __restrict__ pgb, unsigned short* __restrict__ pgBF)
{
    __shared__ __align__(16) unsigned char smem[3 * (A_BUF_B + B_BUF_B)]; // 72 KB

    const int tid  = threadIdx.x;
    const int lane = tid & 63;
    const int w    = tid >> 6;
    const int wr   = w >> 1;
    const int wc   = w & 1;
    const int m0   = blockIdx.x * 256;
    const int n0   = blockIdx.y * 128;
    const int fr   = lane & 15, fq = lane >> 4;

    f32x4 acc[4][4] = {};

    auto Abuf = [&](int b) -> unsigned char* { return smem + b * A_BUF_B; };
    auto Bbuf = [&](int b) -> unsigned char* {
        return smem + 3 * A_BUF_B + b * B_BUF_B; };

    auto stage = [&](int buf, int kt) {
        #pragma unroll
        for (int s = 0; s < 2; ++s) {
            int r = w * 32 + s * 16 + (lane >> 2);
            int ch = (lane & 3) ^ ((r >> 1) & 3);
            int pg_ = kt * 4 + ch;
            int tap = pg_ / 14, pl = pg_ % 14;
            int shift = (tap / 3 - 1) * 66 + (tap % 3) - 1;
            if (pg_ >= 126) { pl = 14; shift = 0; }
            gload_lds16(XTG + ((long)pl * PLANE_ROWS + (long)(m0 + r) + shift) * 8,
                        Abuf(buf) + (w * 32 + s * 16) * 64);
        }
        {
            int r = w * 16 + (lane >> 2);
            int ch = (lane & 3) ^ ((r >> 1) & 3);
            gload_lds16(&B2[(size_t)(n0 + r) * KP + kt * 32 + ch * 8],
                        Bbuf(buf) + (w * 16) * 64);
        }
    };

    stage(0, 0);
    stage(1, 1);

    for (int kt = 0; kt < 32; ++kt) {
        if (kt < 31) asm volatile("s_waitcnt vmcnt(3)" ::: "memory");
        else         asm volatile("s_waitcnt vmcnt(0)" ::: "memory");
        __builtin_amdgcn_s_barrier();
        asm volatile("" ::: "memory");

        const int cur = kt % 3;
        const unsigned char* Ab = Abuf(cur);
        const unsigned char* Bb = Bbuf(cur);

        bf16x8 a[4], b[4];
        #pragma unroll
        for (int mi = 0; mi < 4; ++mi) {
            int r = wr * 64 + mi * 16 + fr;
            a[mi] = *reinterpret_cast<const bf16x8*>(
                Ab + r * 64 + ((fq ^ ((r >> 1) & 3)) << 4));
        }
        #pragma unroll
        for (int ni = 0; ni < 4; ++ni) {
            int r = wc * 64 + ni * 16 + fr;
            b[ni] = *reinterpret_cast<const bf16x8*>(
                Bb + r * 64 + ((fq ^ ((r >> 1) & 3)) << 4));
        }
        if (kt + 2 < 32) stage((kt + 2) % 3, kt + 2);

        __builtin_amdgcn_s_setprio(1);
        #pragma unroll
        for (int mi = 0; mi < 4; ++mi)
            #pragma unroll
            for (int ni = 0; ni < 4; ++ni)
                acc[mi][ni] = __builtin_amdgcn_mfma_f32_16x16x32_bf16(
                    a[mi], b[ni], acc[mi][ni], 0, 0, 0);
        __builtin_amdgcn_s_setprio(0);
    }

    // ---------------- epilogue: LDS transpose + coalesced store -----------
    __builtin_amdgcn_s_barrier();
    unsigned short* T = (unsigned short*)smem;   // [128 oc][264 px]

    #pragma unroll
    for (int ni = 0; ni < 4; ++ni) {
        int ocl = wc * 64 + ni * 16 + fr;
        float bv = (n0 + ocl < PGC) ? pgb[n0 + ocl] : 0.f;
        #pragma unroll
        for (int mi = 0; mi < 4; ++mi) {
            int pxl = wr * 64 + mi * 16 + fq * 4;
            ushort4 pk;
            pk.x = f2bf(acc[mi][ni][0] + bv);
            pk.y = f2bf(acc[mi][ni][1] + bv);
            pk.z = f2bf(acc[mi][ni][2] + bv);
            pk.w = f2bf(acc[mi][ni][3] + bv);
            *reinterpret_cast<ushort4*>(&T[ocl * 264 + pxl]) = pk;
        }
    }
    __builtin_amdgcn_s_barrier();

    const int pxls = tid & 255;
    const int half = tid >> 8;
    const int pxd  = m0 + pxls;
    const int bb   = pxd / XROW;
    const int rem  = pxd - bb * XROW;
    const int yy   = rem / 66 - 1;
    const int xx   = rem - (yy + 1) * 66 - 1;
    const bool valid = (pxd < Bn * XROW) &&
                       ((unsigned)yy < 64u) && ((unsigned)xx < 64u);
    unsigned short* pbase = pgBF + (size_t)bb * PGC * HW + yy * 64 + xx;

    #pragma unroll 4
    for (int oc = 0; oc < 64; ++oc) {
        int ocg = n0 + half * 64 + oc;
        if (ocg >= PGC) break;
        unsigned short v = T[(half * 64 + oc) * 264 + pxls];
        if (valid) pbase[(size_t)ocg * HW] = v;
    }
}

// ---------------------------------------------------------------------------
// fused sample+GEMM v2 (round 20 exact): block = 32 px, BK=64, 16 tiles,
// one tap-task per thread, 40 KB LDS -> 4 blocks/CU, XCD-affine grid.
// ---------------------------------------------------------------------------
__global__ __launch_bounds__(256, 4) void fused_kernel(
    const unsigned short* __restrict__ XTG, const unsigned short* __restrict__ pg,
    const unsigned short* __restrict__ WB, const float* __restrict__ bias,
    float* __restrict__ out)
{
    __shared__ __align__(16) unsigned char Ab[2][32 * 128];   //  8 KB
    __shared__ __align__(16) unsigned char Bb[2][128 * 128];  // 32 KB

    const int tid  = threadIdx.x;
    const int lane = tid & 63;
    const int w    = tid >> 6;
    const int fr   = lane & 15, fq = lane >> 4;

    const int bid = (int)blockIdx.x;
    const int blk = (bid & 7) * 128 + (bid >> 3);
    const int px0 = blk * 32;
    const int b   = px0 >> 12;
    const int hw0 = px0 & 4095;

    const int spx = tid & 31;
    const int q   = tid >> 5;
    const int hw  = hw0 + spx;
    const int sy  = hw >> 6, sx = hw & 63;

    const unsigned short* pgb = pg + (size_t)b * PGC * HW + hw;

    f32x4 acc[2][2] = {};

    unsigned short rdy, rdx, rmv;
    float fdy, fdx, fmv;
    uint4 q00, q01, q10, q11;
    float w00, w01, w10, w11;

    auto issue_pg = [&](int kt) {
        int gk = kt * 8 + q;
        int gkc = min(gk, 125);
        int g = gkc / 9, k = gkc - 9 * g;
        rdy = pgb[(size_t)(18 * g + 2 * k) * HW];
        rdx = pgb[(size_t)(18 * g + 2 * k + 1) * HW];
        rmv = pgb[(size_t)(252 + 9 * g + k) * HW];
    };

    auto issue_gather = [&](int kt1) {
        int gk = kt1 * 8 + q;
        bool valid = gk < 126;
        int gkc = min(gk, 125);
        int g = gkc / 9, k = gkc - 9 * g;
        const int ky = k / 3, kx = k - 3 * ky;
        float m = valid ? 1.f / (1.f + __expf(-fmv)) : 0.f;
        float yf = (float)(sy + ky - 1) + fdy;
        float xf = (float)(sx + kx - 1) + fdx;
        float y0 = floorf(yf), x0 = floorf(xf);
        float wy1 = yf - y0, wx1 = xf - x0;
        float wy0 = 1.f - wy1, wx0 = 1.f - wx1;
        int iy0 = (int)y0, ix0 = (int)x0;
        bool vy0 = (iy0 >= 0) && (iy0 < Hn);
        bool vy1 = (iy0 >= -1) && (iy0 < Hn - 1);
        bool vx0 = (ix0 >= 0) && (ix0 < Wn);
        bool vx1 = (ix0 >= -1) && (ix0 < Wn - 1);
        int cy0 = min(max(iy0, 0), Hn - 1), cy1 = min(max(iy0 + 1, 0), Hn - 1);
        int cx0 = min(max(ix0, 0), Wn - 1), cx1 = min(max(ix0 + 1, 0), Wn - 1);
        w00 = (vy0 && vx0) ? wy0 * wx0 * m : 0.f;
        w01 = (vy0 && vx1) ? wy0 * wx1 * m : 0.f;
        w10 = (vy1 && vx0) ? wy1 * wx0 * m : 0.f;
        w11 = (vy1 && vx1) ? wy1 * wx1 * m : 0.f;
        const unsigned short* xg = XTG +
            ((size_t)g * PLANE_ROWS + (size_t)b * XROW) * 8;
        q00 = *reinterpret_cast<const uint4*>(xg + (size_t)((cy0 + 1) * 66 + cx0 + 1) * 8);
        q01 = *reinterpret_cast<const uint4*>(xg + (size_t)((cy0 + 1) * 66 + cx1 + 1) * 8);
        q10 = *reinterpret_cast<const uint4*>(xg + (size_t)((cy1 + 1) * 66 + cx0 + 1) * 8);
        q11 = *reinterpret_cast<const uint4*>(xg + (size_t)((cy1 + 1) * 66 + cx1 + 1) * 8);
    };

    auto combine_write = [&](int buf) {
        unsigned int c00[4] = {q00.x, q00.y, q00.z, q00.w};
        unsigned int c01[4] = {q01.x, q01.y, q01.z, q01.w};
        unsigned int c10[4] = {q10.x, q10.y, q10.z, q10.w};
        unsigned int c11[4] = {q11.x, q11.y, q11.z, q11.w};
        unsigned int pk[4];
        #pragma unroll
        for (int j = 0; j < 4; ++j) {
            float lo = bflo(c00[j]) * w00 + bflo(c01[j]) * w01 +
                       bflo(c10[j]) * w10 + bflo(c11[j]) * w11;
            float hi = bfhi(c00[j]) * w00 + bfhi(c01[j]) * w01 +
                       bfhi(c10[j]) * w10 + bfhi(c11[j]) * w11;
            pk[j] = (unsigned int)f2bf(lo) | ((unsigned int)f2bf(hi) << 16);
        }
        int slot = q ^ (spx & 7);
        *reinterpret_cast<uint4*>(Ab[buf] + spx * 128 + slot * 16) =
            *reinterpret_cast<const uint4*>(pk);
    };

    auto stageB = [&](int buf, int kt) {
        #pragma unroll
        for (int s = 0; s < 4; ++s) {
            int r = s * 32 + w * 8 + (lane >> 3);
            int ch = (lane & 7) ^ (r & 7);
            gload_lds16(&WB[(size_t)r * KP + kt * 64 + ch * 8],
                        Bb[buf] + (s * 32 + w * 8) * 128);
        }
    };

    auto mfma_tile = [&](int c) {
        #pragma unroll
        for (int ks = 0; ks < 2; ++ks) {
            bf16x8 a[2], bfr[2];
            #pragma unroll
            for (int mi = 0; mi < 2; ++mi) {
                int r = mi * 16 + fr;
                a[mi] = *reinterpret_cast<const bf16x8*>(
                    Ab[c] + r * 128 + (((ks * 4 + fq) ^ (r & 7)) << 4));
            }
            #pragma unroll
            for (int ni = 0; ni < 2; ++ni) {
                int r = w * 32 + ni * 16 + fr;
                bfr[ni] = *reinterpret_cast<const bf16x8*>(
                    Bb[c] + r * 128 + (((ks * 4 + fq) ^ (r & 7)) << 4));
            }
            __builtin_amdgcn_s_setprio(1);
            #pragma unroll
            for (int mi = 0; mi < 2; ++mi)
                #pragma unroll
                for (int ni = 0; ni < 2; ++ni)
                    acc[mi][ni] = __builtin_amdgcn_mfma_f32_16x16x32_bf16(
                        a[mi], bfr[ni], acc[mi][ni], 0, 0, 0);
            __builtin_amdgcn_s_setprio(0);
        }
    };

    issue_pg(0);
    asm volatile("s_waitcnt vmcnt(0)" ::: "memory");
    fdy = bf2f(rdy); fdx = bf2f(rdx); fmv = bf2f(rmv);
    issue_gather(0);
    asm volatile("" ::: "memory");
    stageB(0, 0);
    asm volatile("" ::: "memory");
    issue_pg(1);
    asm volatile("s_waitcnt vmcnt(7)" ::: "memory");
    combine_write(0);
    asm volatile("s_waitcnt vmcnt(0)" ::: "memory");
    fdy = bf2f(rdy); fdx = bf2f(rdx); fmv = bf2f(rmv);
    asm volatile("s_waitcnt lgkmcnt(0)" ::: "memory");
    __builtin_amdgcn_s_barrier();
    asm volatile("" ::: "memory");

    int cur = 0;
    for (int kt = 0; kt < 16; ++kt) {
        if (kt < 15) {
            issue_gather(kt + 1);
            asm volatile("" ::: "memory");
            stageB(cur ^ 1, kt + 1);
            asm volatile("" ::: "memory");
            issue_pg(min(kt + 2, 15));
            asm volatile("" ::: "memory");
        }
        mfma_tile(cur);
        if (kt < 15) {
            asm volatile("s_waitcnt vmcnt(7)" ::: "memory");
            combine_write(cur ^ 1);
            asm volatile("s_waitcnt vmcnt(0)" ::: "memory");
            fdy = bf2f(rdy); fdx = bf2f(rdx); fmv = bf2f(rmv);
            asm volatile("s_waitcnt lgkmcnt(0)" ::: "memory");
            __builtin_amdgcn_s_barrier();
            asm volatile("" ::: "memory");
            cur ^= 1;
        }
    }

    #pragma unroll
    for (int ni = 0; ni < 2; ++ni) {
        int oc = w * 32 + ni * 16 + fr;
        if (oc >= On) continue;
        float bv = bias[oc];
        #pragma unroll
        for (int mi = 0; mi < 2; ++mi) {
            int hwo = hw0 + mi * 16 + fq * 4;
            float4 o;
            o.x = acc[mi][ni][0] + bv;
            o.y = acc[mi][ni][1] + bv;
            o.z = acc[mi][ni][2] + bv;
            o.w = acc[mi][ni][3] + bv;
            *reinterpret_cast<float4*>(
                &out[((size_t)(b * On + oc)) * HW + hwo]) = o;
        }
    }
}

// ---------------------------------------------------------------------------
extern "C" void kernel_launch(void* const* d_in, const int* in_sizes, int n_in,
                              void* d_out, int out_size, void* d_ws, size_t ws_size,
                              hipStream_t stream) {
    const float* x    = (const float*)d_in[0];
    const float* pgw  = (const float*)d_in[1];
    const float* pgb  = (const float*)d_in[2];
    const float* w    = (const float*)d_in[3];
    const float* bias = (const float*)d_in[4];
    float* out = (float*)d_out;

    char* wsb = (char*)d_ws;
    unsigned short* pgBF = (unsigned short*)wsb;                 // 24.77 MB
    size_t off = (size_t)PGC * Bn * HW * 2;
    unsigned short* B2   = (unsigned short*)(wsb + off);         // 0.79 MB
    off += (size_t)NP * KP * 2;
    unsigned short* WB   = (unsigned short*)(wsb + off);         // 0.26 MB
    off += (size_t)128 * KP * 2;
    unsigned short* XTGa = (unsigned short*)(wsb + off);         // 8.93 MB
    unsigned short* XTG  = XTGa + (size_t)XGUARD * 8;            // guarded base

    // prep: zero XTG + build B2 (dense) + WB
    {
        int tot = ZN + B2N + WBN;
        prep_kernel<<<(tot + 255) / 256, 256, 0, stream>>>(pgw, w, XTGa, B2, WB);
    }
    // transpose x -> XTG (group-planar NHWC bf16, 66x66 halo)
    xpose_kernel<<<dim3(Hn, Bn), 256, 0, stream>>>(x, XTG);

    // pg conv: dense-K 256x128/BK=32, 72 KB LDS, 2 blocks/CU (v8, round-18)
    pg_shift_kernel<<<dim3(PG_MT, NP / 128), 512, 0, stream>>>(
        XTG, B2, pgb, pgBF);

    // fused deformable sampling + main GEMM (32-px blocks, 16 waves/CU)
    fused_kernel<<<dim3(1024), 256, 0, stream>>>(XTG, pgBF, WB, bias, out);
}

// Round 23
// 91.746 us; speedup vs baseline: 3.1738x; 1.0026x over previous
//
#include <hip/hip_runtime.h>
#include <math.h>

#define Bn 8
#define Cn 112
#define Hn 64
#define Wn 64
#define On 112
#define Gn 14
#define PGC 378          // 3*G*K2
#define HW 4096          // 64*64
#define CKW 1008         // C*K2
#define KP 1024          // padded K (main GEMM and dense pg GEMM)
#define NP 384           // padded N (oc) for pg GEMM
#define XROW 4356        // 66*66 rows per batch
#define PG_MT 137        // M-tiles of 256
#define MPAD (PG_MT * 256)                 // 35072
#define PLANE_ROWS 34848                   // 8 batches * 4356 rows per plane
#define XGUARD 67
#define XTG_ROWS_TOTAL 558080              // padded alloc rows

typedef __attribute__((ext_vector_type(8))) short bf16x8;
typedef __attribute__((ext_vector_type(4))) float f32x4;

__device__ __forceinline__ unsigned short f2bf(float f) {
    union { float f; unsigned int u; } v; v.f = f;
    unsigned int r = v.u + 0x7fffu + ((v.u >> 16) & 1u);
    return (unsigned short)(r >> 16);
}
__device__ __forceinline__ float bf2f(unsigned short u) {
    union { unsigned int u; float f; } v; v.u = ((unsigned int)u) << 16;
    return v.f;
}
__device__ __forceinline__ float bflo(unsigned int u) {
    union { unsigned int u; float f; } v; v.u = u << 16; return v.f;
}
__device__ __forceinline__ float bfhi(unsigned int u) {
    union { unsigned int u; float f; } v; v.u = u & 0xffff0000u; return v.f;
}
__device__ __forceinline__ void gload_lds16(const void* g, void* l) {
    __builtin_amdgcn_global_load_lds(
        (const __attribute__((address_space(1))) unsigned int*)g,
        (__attribute__((address_space(3))) unsigned int*)l, 16, 0, 0);
}

// ---------------------------------------------------------------------------
// prep (merged): zero XTG alloc | B2 dense [384][1024] | WB [128][1024]
// ---------------------------------------------------------------------------
#define ZN XTG_ROWS_TOTAL
#define B2N (NP * KP)
#define WBN (128 * KP)
__global__ __launch_bounds__(256) void prep_kernel(
    const float* __restrict__ pgw, const float* __restrict__ w,
    unsigned short* __restrict__ XTGa, unsigned short* __restrict__ B2,
    unsigned short* __restrict__ WB)
{
    int t = blockIdx.x * 256 + threadIdx.x;
    if (t < ZN) {
        const uint4 z = {0, 0, 0, 0};
        reinterpret_cast<uint4*>(XTGa)[t] = z;
        return;
    }
    t -= ZN;
    if (t < B2N) {
        int oc = t >> 10, ck = t & 1023;
        int pg_ = ck >> 3, cc = ck & 7;
        int tap = pg_ / 14, pl = pg_ % 14;
        float v = (pg_ < 126 && oc < PGC)
            ? pgw[(size_t)oc * CKW + (pl * 8 + cc) * 9 + tap] : 0.f;
        B2[t] = f2bf(v);
        return;
    }
    t -= B2N;
    if (t < WBN) {
        int oc = t >> 10, ck = t & 1023;
        float v = 0.f;
        if (oc < On && ck < CKW) {
            int g = ck / 72, r = ck % 72;
            int k = r >> 3, cc = r & 7;
            v = w[(size_t)oc * CKW + (g * 8 + cc) * 9 + k];
        }
        WB[t] = f2bf(v);
    }
}

// ---------------------------------------------------------------------------
// xpose: x NCHW f32 -> XTG bf16 planes [g][b][row66x66][8ch]
// ---------------------------------------------------------------------------
__global__ __launch_bounds__(256) void xpose_kernel(
    const float* __restrict__ x, unsigned short* __restrict__ XTG)
{
    __shared__ unsigned short lds[64][136];

    const int tid = threadIdx.x;
    const int y = blockIdx.x, b = blockIdx.y;
    const int xx = tid & 63, cw = tid >> 6;

    const float* xb = x + (size_t)b * Cn * HW + y * 64;
    #pragma unroll
    for (int p = 0; p < 28; ++p) {
        int c = p * 4 + cw;
        lds[xx][c] = f2bf(xb[(size_t)c * HW + xx]);
    }
    __syncthreads();

    #pragma unroll
    for (int q = 0; q < 4; ++q) {
        int task = q * 256 + tid;
        if (task < 896) {
            int g = task >> 6;
            int x2 = task & 63;
            unsigned short* dst = XTG + ((size_t)g * PLANE_ROWS
                + (size_t)b * XROW + (y + 1) * 66 + x2 + 1) * 8;
            *reinterpret_cast<uint4*>(dst) =
                *reinterpret_cast<const uint4*>(&lds[x2][g * 8]);
        }
    }
}

// ---------------------------------------------------------------------------
// pg shift-GEMM v8 (round 18 exact: 3 buffers, 72 KB, (512,4), ~49 us)
// ---------------------------------------------------------------------------
#define A_BUF_B 16384
#define B_BUF_B 8192
__global__ __launch_bounds__(512, 4) void pg_shift_kernel(
    const unsigned short* __restrict__ XTG, const unsigned short* __restrict__ B2,
    const float* __restrict__ pgb, unsigned short* __restrict__ pgBF)
{
    __shared__ __align__(16) unsigned char smem[3 * (A_BUF_B + B_BUF_B)]; // 72 KB

    const int tid  = threadIdx.x;
    const int lane = tid & 63;
    const int w    = tid >> 6;
    const int wr   = w >> 1;
    const int wc   = w & 1;
    const int m0   = blockIdx.x * 256;
    const int n0   = blockIdx.y * 128;
    const int fr   = lane & 15, fq = lane >> 4;

    f32x4 acc[4][4] = {};

    auto Abuf = [&](int b) -> unsigned char* { return smem + b * A_BUF_B; };
    auto Bbuf = [&](int b) -> unsigned char* {
        return smem + 3 * A_BUF_B + b * B_BUF_B; };

    auto stage = [&](int buf, int kt) {
        #pragma unroll
        for (int s = 0; s < 2; ++s) {
            int r = w * 32 + s * 16 + (lane >> 2);
            int ch = (lane & 3) ^ ((r >> 1) & 3);
            int pg_ = kt * 4 + ch;
            int tap = pg_ / 14, pl = pg_ % 14;
            int shift = (tap / 3 - 1) * 66 + (tap % 3) - 1;
            if (pg_ >= 126) { pl = 14; shift = 0; }
            gload_lds16(XTG + ((long)pl * PLANE_ROWS + (long)(m0 + r) + shift) * 8,
                        Abuf(buf) + (w * 32 + s * 16) * 64);
        }
        {
            int r = w * 16 + (lane >> 2);
            int ch = (lane & 3) ^ ((r >> 1) & 3);
            gload_lds16(&B2[(size_t)(n0 + r) * KP + kt * 32 + ch * 8],
                        Bbuf(buf) + (w * 16) * 64);
        }
    };

    stage(0, 0);
    stage(1, 1);

    for (int kt = 0; kt < 32; ++kt) {
        if (kt < 31) asm volatile("s_waitcnt vmcnt(3)" ::: "memory");
        else         asm volatile("s_waitcnt vmcnt(0)" ::: "memory");
        __builtin_amdgcn_s_barrier();
        asm volatile("" ::: "memory");

        const int cur = kt % 3;
        const unsigned char* Ab = Abuf(cur);
        const unsigned char* Bb = Bbuf(cur);

        bf16x8 a[4], b[4];
        #pragma unroll
        for (int mi = 0; mi < 4; ++mi) {
            int r = wr * 64 + mi * 16 + fr;
            a[mi] = *reinterpret_cast<const bf16x8*>(
                Ab + r * 64 + ((fq ^ ((r >> 1) & 3)) << 4));
        }
        #pragma unroll
        for (int ni = 0; ni < 4; ++ni) {
            int r = wc * 64 + ni * 16 + fr;
            b[ni] = *reinterpret_cast<const bf16x8*>(
                Bb + r * 64 + ((fq ^ ((r >> 1) & 3)) << 4));
        }
        if (kt + 2 < 32) stage((kt + 2) % 3, kt + 2);

        __builtin_amdgcn_s_setprio(1);
        #pragma unroll
        for (int mi = 0; mi < 4; ++mi)
            #pragma unroll
            for (int ni = 0; ni < 4; ++ni)
                acc[mi][ni] = __builtin_amdgcn_mfma_f32_16x16x32_bf16(
                    a[mi], b[ni], acc[mi][ni], 0, 0, 0);
        __builtin_amdgcn_s_setprio(0);
    }

    // ---------------- epilogue: LDS transpose + coalesced store -----------
    __builtin_amdgcn_s_barrier();
    unsigned short* T = (unsigned short*)smem;   // [128 oc][264 px]

    #pragma unroll
    for (int ni = 0; ni < 4; ++ni) {
        int ocl = wc * 64 + ni * 16 + fr;
        float bv = (n0 + ocl < PGC) ? pgb[n0 + ocl] : 0.f;
        #pragma unroll
        for (int mi = 0; mi < 4; ++mi) {
            int pxl = wr * 64 + mi * 16 + fq * 4;
            ushort4 pk;
            pk.x = f2bf(acc[mi][ni][0] + bv);
            pk.y = f2bf(acc[mi][ni][1] + bv);
            pk.z = f2bf(acc[mi][ni][2] + bv);
            pk.w = f2bf(acc[mi][ni][3] + bv);
            *reinterpret_cast<ushort4*>(&T[ocl * 264 + pxl]) = pk;
        }
    }
    __builtin_amdgcn_s_barrier();

    const int pxls = tid & 255;
    const int half = tid >> 8;
    const int pxd  = m0 + pxls;
    const int bb   = pxd / XROW;
    const int rem  = pxd - bb * XROW;
    const int yy   = rem / 66 - 1;
    const int xx   = rem - (yy + 1) * 66 - 1;
    const bool valid = (pxd < Bn * XROW) &&
                       ((unsigned)yy < 64u) && ((unsigned)xx < 64u);
    unsigned short* pbase = pgBF + (size_t)bb * PGC * HW + yy * 64 + xx;

    #pragma unroll 4
    for (int oc = 0; oc < 64; ++oc) {
        int ocg = n0 + half * 64 + oc;
        if (ocg >= PGC) break;
        unsigned short v = T[(half * 64 + oc) * 264 + pxls];
        if (valid) pbase[(size_t)ocg * HW] = v;
    }
}

// ---------------------------------------------------------------------------
// fused sample+GEMM v3: block = 64 px x 8 waves (512 thr), BK=64 (16 K-tiles
// of 8 taps x 8ch, one tap-task per thread, wave = tap slot).
// LDS 48 KB -> 3 blocks/CU (24 waves/CU); grid 512 all-resident,
// XCD-affine = 1 batch per XCD.  2-deep pg pipeline, counted vmcnt(5),
// 1 barrier/tile; swizzle chunk ^= row&7 (both sides, rule 21).
// Per-wave MFMA: M-half (w>>2) x N-quarter (w&3), acc 2x2 frags.
// ---------------------------------------------------------------------------
__global__ __launch_bounds__(512, 4) void fused_kernel(
    const unsigned short* __restrict__ XTG, const unsigned short* __restrict__ pg,
    const unsigned short* __restrict__ WB, const float* __restrict__ bias,
    float* __restrict__ out)
{
    __shared__ __align__(16) unsigned char Ab[2][64 * 128];   // 16 KB
    __shared__ __align__(16) unsigned char Bb[2][128 * 128];  // 32 KB

    const int tid  = threadIdx.x;
    const int lane = tid & 63;
    const int w    = tid >> 6;          // 0..7 = wave = tap slot
    const int fr   = lane & 15, fq = lane >> 4;
    const int mh   = w >> 2;            // M half
    const int nq   = w & 3;             // N quarter

    const int bid = (int)blockIdx.x;
    const int blk = (bid & 7) * 64 + (bid >> 3);   // XCD-affine (512 = 8*64)
    const int px0 = blk * 64;
    const int b   = px0 >> 12;
    const int hw0 = px0 & 4095;

    const int spx = lane;               // sampling pixel within block
    const int q   = w;                  // tap slot 0..7
    const int hw  = hw0 + spx;
    const int sy  = hw >> 6, sx = hw & 63;

    const unsigned short* pgb = pg + (size_t)b * PGC * HW + hw;

    f32x4 acc[2][2] = {};

    unsigned short rdy, rdx, rmv;       // raw pg loads (tile t+2)
    float fdy, fdx, fmv;                // converted pg (tile t+1)
    uint4 q00, q01, q10, q11;           // gathers in flight (tile t+1)
    float w00, w01, w10, w11;           // weights (tile t+1)

    auto issue_pg = [&](int kt) {
        int gk = kt * 8 + q;
        int gkc = min(gk, 125);
        int g = gkc / 9, k = gkc - 9 * g;
        rdy = pgb[(size_t)(18 * g + 2 * k) * HW];
        rdx = pgb[(size_t)(18 * g + 2 * k + 1) * HW];
        rmv = pgb[(size_t)(252 + 9 * g + k) * HW];
    };

    auto issue_gather = [&](int kt1) {
        int gk = kt1 * 8 + q;
        bool valid = gk < 126;
        int gkc = min(gk, 125);
        int g = gkc / 9, k = gkc - 9 * g;
        const int ky = k / 3, kx = k - 3 * ky;
        float m = valid ? 1.f / (1.f + __expf(-fmv)) : 0.f;
        float yf = (float)(sy + ky - 1) + fdy;
        float xf = (float)(sx + kx - 1) + fdx;
        float y0 = floorf(yf), x0 = floorf(xf);
        float wy1 = yf - y0, wx1 = xf - x0;
        float wy0 = 1.f - wy1, wx0 = 1.f - wx1;
        int iy0 = (int)y0, ix0 = (int)x0;
        bool vy0 = (iy0 >= 0) && (iy0 < Hn);
        bool vy1 = (iy0 >= -1) && (iy0 < Hn - 1);
        bool vx0 = (ix0 >= 0) && (ix0 < Wn);
        bool vx1 = (ix0 >= -1) && (ix0 < Wn - 1);
        int cy0 = min(max(iy0, 0), Hn - 1), cy1 = min(max(iy0 + 1, 0), Hn - 1);
        int cx0 = min(max(ix0, 0), Wn - 1), cx1 = min(max(ix0 + 1, 0), Wn - 1);
        w00 = (vy0 && vx0) ? wy0 * wx0 * m : 0.f;
        w01 = (vy0 && vx1) ? wy0 * wx1 * m : 0.f;
        w10 = (vy1 && vx0) ? wy1 * wx0 * m : 0.f;
        w11 = (vy1 && vx1) ? wy1 * wx1 * m : 0.f;
        const unsigned short* xg = XTG +
            ((size_t)g * PLANE_ROWS + (size_t)b * XROW) * 8;
        q00 = *reinterpret_cast<const uint4*>(xg + (size_t)((cy0 + 1) * 66 + cx0 + 1) * 8);
        q01 = *reinterpret_cast<const uint4*>(xg + (size_t)((cy0 + 1) * 66 + cx1 + 1) * 8);
        q10 = *reinterpret_cast<const uint4*>(xg + (size_t)((cy1 + 1) * 66 + cx0 + 1) * 8);
        q11 = *reinterpret_cast<const uint4*>(xg + (size_t)((cy1 + 1) * 66 + cx1 + 1) * 8);
    };

    auto combine_write = [&](int buf) {
        unsigned int c00[4] = {q00.x, q00.y, q00.z, q00.w};
        unsigned int c01[4] = {q01.x, q01.y, q01.z, q01.w};
        unsigned int c10[4] = {q10.x, q10.y, q10.z, q10.w};
        unsigned int c11[4] = {q11.x, q11.y, q11.z, q11.w};
        unsigned int pk[4];
        #pragma unroll
        for (int j = 0; j < 4; ++j) {
            float lo = bflo(c00[j]) * w00 + bflo(c01[j]) * w01 +
                       bflo(c10[j]) * w10 + bflo(c11[j]) * w11;
            float hi = bfhi(c00[j]) * w00 + bfhi(c01[j]) * w01 +
                       bfhi(c10[j]) * w10 + bfhi(c11[j]) * w11;
            pk[j] = (unsigned int)f2bf(lo) | ((unsigned int)f2bf(hi) << 16);
        }
        int slot = q ^ (spx & 7);
        *reinterpret_cast<uint4*>(Ab[buf] + spx * 128 + slot * 16) =
            *reinterpret_cast<const uint4*>(pk);
    };

    auto stageB = [&](int buf, int kt) {
        #pragma unroll
        for (int s = 0; s < 2; ++s) {
            int r = s * 64 + w * 8 + (lane >> 3);
            int ch = (lane & 7) ^ (r & 7);
            gload_lds16(&WB[(size_t)r * KP + kt * 64 + ch * 8],
                        Bb[buf] + (s * 64 + w * 8) * 128);
        }
    };

    auto mfma_tile = [&](int c) {
        #pragma unroll
        for (int ks = 0; ks < 2; ++ks) {
            bf16x8 a[2], bfr[2];
            #pragma unroll
            for (int mi = 0; mi < 2; ++mi) {
                int r = mh * 32 + mi * 16 + fr;
                a[mi] = *reinterpret_cast<const bf16x8*>(
                    Ab[c] + r * 128 + (((ks * 4 + fq) ^ (r & 7)) << 4));
            }
            #pragma unroll
            for (int ni = 0; ni < 2; ++ni) {
                int r = nq * 32 + ni * 16 + fr;
                bfr[ni] = *reinterpret_cast<const bf16x8*>(
                    Bb[c] + r * 128 + (((ks * 4 + fq) ^ (r & 7)) << 4));
            }
            __builtin_amdgcn_s_setprio(1);
            #pragma unroll
            for (int mi = 0; mi < 2; ++mi)
                #pragma unroll
                for (int ni = 0; ni < 2; ++ni)
                    acc[mi][ni] = __builtin_amdgcn_mfma_f32_16x16x32_bf16(
                        a[mi], bfr[ni], acc[mi][ni], 0, 0, 0);
            __builtin_amdgcn_s_setprio(0);
        }
    };

    // ---- prologue: tile 0 into buffers, pg floats for tile 1 ----
    issue_pg(0);
    asm volatile("s_waitcnt vmcnt(0)" ::: "memory");
    fdy = bf2f(rdy); fdx = bf2f(rdx); fmv = bf2f(rmv);
    issue_gather(0);
    asm volatile("" ::: "memory");
    stageB(0, 0);
    asm volatile("" ::: "memory");
    issue_pg(1);
    asm volatile("s_waitcnt vmcnt(5)" ::: "memory");   // gathers(0) done
    combine_write(0);
    asm volatile("s_waitcnt vmcnt(0)" ::: "memory");
    fdy = bf2f(rdy); fdx = bf2f(rdx); fmv = bf2f(rmv); // tile 1
    asm volatile("s_waitcnt lgkmcnt(0)" ::: "memory");
    __builtin_amdgcn_s_barrier();
    asm volatile("" ::: "memory");

    int cur = 0;
    for (int kt = 0; kt < 16; ++kt) {
        if (kt < 15) {
            issue_gather(kt + 1);                       // 4 dwordx4
            asm volatile("" ::: "memory");
            stageB(cur ^ 1, kt + 1);                    // 2 gload_lds
            asm volatile("" ::: "memory");
            issue_pg(min(kt + 2, 15));                  // 3 ushort loads
            asm volatile("" ::: "memory");
        }
        mfma_tile(cur);
        if (kt < 15) {
            asm volatile("s_waitcnt vmcnt(5)" ::: "memory");   // gathers done
            combine_write(cur ^ 1);
            asm volatile("s_waitcnt vmcnt(0)" ::: "memory");   // B + pg done
            fdy = bf2f(rdy); fdx = bf2f(rdx); fmv = bf2f(rmv);
            asm volatile("s_waitcnt lgkmcnt(0)" ::: "memory");
            __builtin_amdgcn_s_barrier();
            asm volatile("" ::: "memory");
            cur ^= 1;
        }
    }

    // ---- epilogue: fp32 out + bias ----
    #pragma unroll
    for (int ni = 0; ni < 2; ++ni) {
        int oc = nq * 32 + ni * 16 + fr;
        if (oc >= On) continue;
        float bv = bias[oc];
        #pragma unroll
        for (int mi = 0; mi < 2; ++mi) {
            int hwo = hw0 + mh * 32 + mi * 16 + fq * 4;
            float4 o;
            o.x = acc[mi][ni][0] + bv;
            o.y = acc[mi][ni][1] + bv;
            o.z = acc[mi][ni][2] + bv;
            o.w = acc[mi][ni][3] + bv;
            *reinterpret_cast<float4*>(
                &out[((size_t)(b * On + oc)) * HW + hwo]) = o;
        }
    }
}

// ---------------------------------------------------------------------------
extern "C" void kernel_launch(void* const* d_in, const int* in_sizes, int n_in,
                              void* d_out, int out_size, void* d_ws, size_t ws_size,
                              hipStream_t stream) {
    const float* x    = (const float*)d_in[0];
    const float* pgw  = (const float*)d_in[1];
    const float* pgb  = (const float*)d_in[2];
    const float* w    = (const float*)d_in[3];
    const float* bias = (const float*)d_in[4];
    float* out = (float*)d_out;

    char* wsb = (char*)d_ws;
    unsigned short* pgBF = (unsigned short*)wsb;                 // 24.77 MB
    size_t off = (size_t)PGC * Bn * HW * 2;
    unsigned short* B2   = (unsigned short*)(wsb + off);         // 0.79 MB
    off += (size_t)NP * KP * 2;
    unsigned short* WB   = (unsigned short*)(wsb + off);         // 0.26 MB
    off += (size_t)128 * KP * 2;
    unsigned short* XTGa = (unsigned short*)(wsb + off);         // 8.93 MB
    unsigned short* XTG  = XTGa + (size_t)XGUARD * 8;            // guarded base

    // prep: zero XTG + build B2 (dense) + WB
    {
        int tot = ZN + B2N + WBN;
        prep_kernel<<<(tot + 255) / 256, 256, 0, stream>>>(pgw, w, XTGa, B2, WB);
    }
    // transpose x -> XTG (group-planar NHWC bf16, 66x66 halo)
    xpose_kernel<<<dim3(Hn, Bn), 256, 0, stream>>>(x, XTG);

    // pg conv: dense-K 256x128/BK=32, 72 KB LDS, 2 blocks/CU (v8, round-18)
    pg_shift_kernel<<<dim3(PG_MT, NP / 128), 512, 0, stream>>>(
        XTG, B2, pgb, pgBF);

    // fused deformable sampling + main GEMM (64-px blocks, 24 waves/CU)
    fused_kernel<<<dim3(512), 512, 0, stream>>>(XTG, pgBF, WB, bias, out);
}

// Round 24
// 88.012 us; speedup vs baseline: 3.3085x; 1.0424x over previous
//
#include <hip/hip_runtime.h>
#include <math.h>

#define Bn 8
#define Cn 112
#define Hn 64
#define Wn 64
#define On 112
#define Gn 14
#define PGC 378          // 3*G*K2
#define HW 4096          // 64*64
#define CKW 1008         // C*K2
#define KP 1024          // padded K (main GEMM and dense pg GEMM)
#define NP 384           // padded N (oc) for pg GEMM
#define XROW 4356        // 66*66 rows per batch
#define PG_MT 137        // M-tiles of 256
#define MPAD (PG_MT * 256)                 // 35072
#define PLANE_ROWS 34848                   // 8 batches * 4356 rows per plane
#define XGUARD 67
#define XTG_ROWS_TOTAL 558080              // padded alloc rows

typedef __attribute__((ext_vector_type(8))) short bf16x8;
typedef __attribute__((ext_vector_type(4))) float f32x4;

__device__ __forceinline__ unsigned short f2bf(float f) {
    union { float f; unsigned int u; } v; v.f = f;
    unsigned int r = v.u + 0x7fffu + ((v.u >> 16) & 1u);
    return (unsigned short)(r >> 16);
}
__device__ __forceinline__ float bf2f(unsigned short u) {
    union { unsigned int u; float f; } v; v.u = ((unsigned int)u) << 16;
    return v.f;
}
__device__ __forceinline__ float bflo(unsigned int u) {
    union { unsigned int u; float f; } v; v.u = u << 16; return v.f;
}
__device__ __forceinline__ float bfhi(unsigned int u) {
    union { unsigned int u; float f; } v; v.u = u & 0xffff0000u; return v.f;
}
__device__ __forceinline__ void gload_lds16(const void* g, void* l) {
    __builtin_amdgcn_global_load_lds(
        (const __attribute__((address_space(1))) unsigned int*)g,
        (__attribute__((address_space(3))) unsigned int*)l, 16, 0, 0);
}

// ---------------------------------------------------------------------------
// prep (merged): zero XTG alloc | B2 dense [384][1024] | WB [128][1024]
// ---------------------------------------------------------------------------
#define ZN XTG_ROWS_TOTAL
#define B2N (NP * KP)
#define WBN (128 * KP)
__global__ __launch_bounds__(256) void prep_kernel(
    const float* __restrict__ pgw, const float* __restrict__ w,
    unsigned short* __restrict__ XTGa, unsigned short* __restrict__ B2,
    unsigned short* __restrict__ WB)
{
    int t = blockIdx.x * 256 + threadIdx.x;
    if (t < ZN) {
        const uint4 z = {0, 0, 0, 0};
        reinterpret_cast<uint4*>(XTGa)[t] = z;
        return;
    }
    t -= ZN;
    if (t < B2N) {
        int oc = t >> 10, ck = t & 1023;
        int pg_ = ck >> 3, cc = ck & 7;
        int tap = pg_ / 14, pl = pg_ % 14;
        float v = (pg_ < 126 && oc < PGC)
            ? pgw[(size_t)oc * CKW + (pl * 8 + cc) * 9 + tap] : 0.f;
        B2[t] = f2bf(v);
        return;
    }
    t -= B2N;
    if (t < WBN) {
        int oc = t >> 10, ck = t & 1023;
        float v = 0.f;
        if (oc < On && ck < CKW) {
            int g = ck / 72, r = ck % 72;
            int k = r >> 3, cc = r & 7;
            v = w[(size_t)oc * CKW + (g * 8 + cc) * 9 + k];
        }
        WB[t] = f2bf(v);
    }
}

// ---------------------------------------------------------------------------
// xpose: x NCHW f32 -> XTG bf16 planes [g][b][row66x66][8ch]
// ---------------------------------------------------------------------------
__global__ __launch_bounds__(256) void xpose_kernel(
    const float* __restrict__ x, unsigned short* __restrict__ XTG)
{
    __shared__ unsigned short lds[64][136];

    const int tid = threadIdx.x;
    const int y = blockIdx.x, b = blockIdx.y;
    const int xx = tid & 63, cw = tid >> 6;

    const float* xb = x + (size_t)b * Cn * HW + y * 64;
    #pragma unroll
    for (int p = 0; p < 28; ++p) {
        int c = p * 4 + cw;
        lds[xx][c] = f2bf(xb[(size_t)c * HW + xx]);
    }
    __syncthreads();

    #pragma unroll
    for (int q = 0; q < 4; ++q) {
        int task = q * 256 + tid;
        if (task < 896) {
            int g = task >> 6;
            int x2 = task & 63;
            unsigned short* dst = XTG + ((size_t)g * PLANE_ROWS
                + (size_t)b * XROW + (y + 1) * 66 + x2 + 1) * 8;
            *reinterpret_cast<uint4*>(dst) =
                *reinterpret_cast<const uint4*>(&lds[x2][g * 8]);
        }
    }
}

// ---------------------------------------------------------------------------
// pg shift-GEMM v10: dense-K (1024), BK=32, 256x128 tile, 8 waves,
// per-wave 64x64.  A-operand DIRECT from XTG (L2) into double-buffered
// registers (planar layout makes each fragment a contiguous 256B segment
// per 16-lane group) -- A never touches LDS.  B through 3 LDS buffers
// (8 KB each), staged 2 tiles ahead (1 gload_lds/thread/tile), counted
// vmcnt(1).  LDS reads per wave-tile: 8 -> 4.
// Epilogue: LDS transpose T[128 oc][264 px] + coalesced store (v8 exact).
// ---------------------------------------------------------------------------
#define B_BUF_B 8192
__global__ __launch_bounds__(512, 4) void pg_shift_kernel(
    const unsigned short* __restrict__ XTG, const unsigned short* __restrict__ B2,
    const float* __restrict__ pgb, unsigned short* __restrict__ pgBF)
{
    __shared__ __align__(16) unsigned char smem[128 * 264 * 2];  // 67.6 KB
    // B buffers live in the front 3*8 KB of smem; T overlays it in epilogue.

    const int tid  = threadIdx.x;
    const int lane = tid & 63;
    const int w    = tid >> 6;
    const int wr   = w >> 1;
    const int wc   = w & 1;
    const int m0   = blockIdx.x * 256;
    const int n0   = blockIdx.y * 128;
    const int fr   = lane & 15, fq = lane >> 4;

    f32x4 acc[4][4] = {};
    bf16x8 aFA[4], aFB[4];

    auto Bbuf = [&](int b) -> unsigned char* { return smem + b * B_BUF_B; };

    auto stageB = [&](int buf, int kt) {
        int r = w * 16 + (lane >> 2);
        int ch = (lane & 3) ^ ((r >> 1) & 3);
        gload_lds16(&B2[(size_t)(n0 + r) * KP + kt * 32 + ch * 8],
                    Bbuf(buf) + (w * 16) * 64);
    };

    // load the 4 A fragments of tile kt into dst (plain global loads)
    auto loadA = [&](int kt, bf16x8 (&dst)[4]) {
        int pg_ = kt * 4 + fq;
        int tap = pg_ / 14, pl = pg_ % 14;
        int shift = (tap / 3 - 1) * 66 + (tap % 3) - 1;
        if (pg_ >= 126) { pl = 14; shift = 0; }
        const unsigned short* base = XTG +
            ((long)pl * PLANE_ROWS + (long)(m0 + shift)) * 8;
        #pragma unroll
        for (int mi = 0; mi < 4; ++mi) {
            long r = wr * 64 + mi * 16 + fr;
            dst[mi] = *reinterpret_cast<const bf16x8*>(base + r * 8);
        }
    };

    auto tile_body = [&](int kt, bf16x8 (&aUse)[4], bf16x8 (&aNext)[4]) {
        if (kt + 1 < 32) loadA(kt + 1, aNext);
        asm volatile("" ::: "memory");            // pin: A loads before B stage
        if (kt + 2 < 32) stageB((kt + 2) % 3, kt + 2);
        asm volatile("" ::: "memory");

        const unsigned char* Bb = Bbuf(kt % 3);
        bf16x8 b[4];
        #pragma unroll
        for (int ni = 0; ni < 4; ++ni) {
            int r = wc * 64 + ni * 16 + fr;
            b[ni] = *reinterpret_cast<const bf16x8*>(
                Bb + r * 64 + ((fq ^ ((r >> 1) & 3)) << 4));
        }
        __builtin_amdgcn_s_setprio(1);
        #pragma unroll
        for (int mi = 0; mi < 4; ++mi)
            #pragma unroll
            for (int ni = 0; ni < 4; ++ni)
                acc[mi][ni] = __builtin_amdgcn_mfma_f32_16x16x32_bf16(
                    aUse[mi], b[ni], acc[mi][ni], 0, 0, 0);
        __builtin_amdgcn_s_setprio(0);

        // B(kt+2) is the youngest VMEM issue -> leave exactly it in flight
        if (kt + 2 < 32) asm volatile("s_waitcnt vmcnt(1)" ::: "memory");
        else             asm volatile("s_waitcnt vmcnt(0)" ::: "memory");
        asm volatile("s_waitcnt lgkmcnt(0)" ::: "memory");
        __builtin_amdgcn_s_barrier();
        asm volatile("" ::: "memory");
    };

    // prologue: B(0), B(1) staged; A(0) in regs
    stageB(0, 0);
    stageB(1, 1);
    loadA(0, aFA);
    asm volatile("s_waitcnt vmcnt(0)" ::: "memory");
    __builtin_amdgcn_s_barrier();
    asm volatile("" ::: "memory");

    for (int kt = 0; kt < 32; kt += 2) {
        tile_body(kt,     aFA, aFB);
        tile_body(kt + 1, aFB, aFA);
    }

    // ---------------- epilogue: LDS transpose + coalesced store -----------
    unsigned short* T = (unsigned short*)smem;   // [128 oc][264 px]

    #pragma unroll
    for (int ni = 0; ni < 4; ++ni) {
        int ocl = wc * 64 + ni * 16 + fr;
        float bv = (n0 + ocl < PGC) ? pgb[n0 + ocl] : 0.f;
        #pragma unroll
        for (int mi = 0; mi < 4; ++mi) {
            int pxl = wr * 64 + mi * 16 + fq * 4;
            ushort4 pk;
            pk.x = f2bf(acc[mi][ni][0] + bv);
            pk.y = f2bf(acc[mi][ni][1] + bv);
            pk.z = f2bf(acc[mi][ni][2] + bv);
            pk.w = f2bf(acc[mi][ni][3] + bv);
            *reinterpret_cast<ushort4*>(&T[ocl * 264 + pxl]) = pk;
        }
    }
    __builtin_amdgcn_s_barrier();

    const int pxls = tid & 255;
    const int half = tid >> 8;
    const int pxd  = m0 + pxls;
    const int bb   = pxd / XROW;
    const int rem  = pxd - bb * XROW;
    const int yy   = rem / 66 - 1;
    const int xx   = rem - (yy + 1) * 66 - 1;
    const bool valid = (pxd < Bn * XROW) &&
                       ((unsigned)yy < 64u) && ((unsigned)xx < 64u);
    unsigned short* pbase = pgBF + (size_t)bb * PGC * HW + yy * 64 + xx;

    #pragma unroll 4
    for (int oc = 0; oc < 64; ++oc) {
        int ocg = n0 + half * 64 + oc;
        if (ocg >= PGC) break;
        unsigned short v = T[(half * 64 + oc) * 264 + pxls];
        if (valid) pbase[(size_t)ocg * HW] = v;
    }
}

// ---------------------------------------------------------------------------
// fused sample+GEMM v3 (round 23): block = 64 px x 8 waves (512 thr), BK=64,
// 16 K-tiles, one tap-task per thread, 48 KB LDS, XCD-affine grid.
// ---------------------------------------------------------------------------
__global__ __launch_bounds__(512, 4) void fused_kernel(
    const unsigned short* __restrict__ XTG, const unsigned short* __restrict__ pg,
    const unsigned short* __restrict__ WB, const float* __restrict__ bias,
    float* __restrict__ out)
{
    __shared__ __align__(16) unsigned char Ab[2][64 * 128];   // 16 KB
    __shared__ __align__(16) unsigned char Bb[2][128 * 128];  // 32 KB

    const int tid  = threadIdx.x;
    const int lane = tid & 63;
    const int w    = tid >> 6;          // 0..7 = wave = tap slot
    const int fr   = lane & 15, fq = lane >> 4;
    const int mh   = w >> 2;            // M half
    const int nq   = w & 3;             // N quarter

    const int bid = (int)blockIdx.x;
    const int blk = (bid & 7) * 64 + (bid >> 3);   // XCD-affine (512 = 8*64)
    const int px0 = blk * 64;
    const int b   = px0 >> 12;
    const int hw0 = px0 & 4095;

    const int spx = lane;               // sampling pixel within block
    const int q   = w;                  // tap slot 0..7
    const int hw  = hw0 + spx;
    const int sy  = hw >> 6, sx = hw & 63;

    const unsigned short* pgb = pg + (size_t)b * PGC * HW + hw;

    f32x4 acc[2][2] = {};

    unsigned short rdy, rdx, rmv;
    float fdy, fdx, fmv;
    uint4 q00, q01, q10, q11;
    float w00, w01, w10, w11;

    auto issue_pg = [&](int kt) {
        int gk = kt * 8 + q;
        int gkc = min(gk, 125);
        int g = gkc / 9, k = gkc - 9 * g;
        rdy = pgb[(size_t)(18 * g + 2 * k) * HW];
        rdx = pgb[(size_t)(18 * g + 2 * k + 1) * HW];
        rmv = pgb[(size_t)(252 + 9 * g + k) * HW];
    };

    auto issue_gather = [&](int kt1) {
        int gk = kt1 * 8 + q;
        bool valid = gk < 126;
        int gkc = min(gk, 125);
        int g = gkc / 9, k = gkc - 9 * g;
        const int ky = k / 3, kx = k - 3 * ky;
        float m = valid ? 1.f / (1.f + __expf(-fmv)) : 0.f;
        float yf = (float)(sy + ky - 1) + fdy;
        float xf = (float)(sx + kx - 1) + fdx;
        float y0 = floorf(yf), x0 = floorf(xf);
        float wy1 = yf - y0, wx1 = xf - x0;
        float wy0 = 1.f - wy1, wx0 = 1.f - wx1;
        int iy0 = (int)y0, ix0 = (int)x0;
        bool vy0 = (iy0 >= 0) && (iy0 < Hn);
        bool vy1 = (iy0 >= -1) && (iy0 < Hn - 1);
        bool vx0 = (ix0 >= 0) && (ix0 < Wn);
        bool vx1 = (ix0 >= -1) && (ix0 < Wn - 1);
        int cy0 = min(max(iy0, 0), Hn - 1), cy1 = min(max(iy0 + 1, 0), Hn - 1);
        int cx0 = min(max(ix0, 0), Wn - 1), cx1 = min(max(ix0 + 1, 0), Wn - 1);
        w00 = (vy0 && vx0) ? wy0 * wx0 * m : 0.f;
        w01 = (vy0 && vx1) ? wy0 * wx1 * m : 0.f;
        w10 = (vy1 && vx0) ? wy1 * wx0 * m : 0.f;
        w11 = (vy1 && vx1) ? wy1 * wx1 * m : 0.f;
        const unsigned short* xg = XTG +
            ((size_t)g * PLANE_ROWS + (size_t)b * XROW) * 8;
        q00 = *reinterpret_cast<const uint4*>(xg + (size_t)((cy0 + 1) * 66 + cx0 + 1) * 8);
        q01 = *reinterpret_cast<const uint4*>(xg + (size_t)((cy0 + 1) * 66 + cx1 + 1) * 8);
        q10 = *reinterpret_cast<const uint4*>(xg + (size_t)((cy1 + 1) * 66 + cx0 + 1) * 8);
        q11 = *reinterpret_cast<const uint4*>(xg + (size_t)((cy1 + 1) * 66 + cx1 + 1) * 8);
    };

    auto combine_write = [&](int buf) {
        unsigned int c00[4] = {q00.x, q00.y, q00.z, q00.w};
        unsigned int c01[4] = {q01.x, q01.y, q01.z, q01.w};
        unsigned int c10[4] = {q10.x, q10.y, q10.z, q10.w};
        unsigned int c11[4] = {q11.x, q11.y, q11.z, q11.w};
        unsigned int pk[4];
        #pragma unroll
        for (int j = 0; j < 4; ++j) {
            float lo = bflo(c00[j]) * w00 + bflo(c01[j]) * w01 +
                       bflo(c10[j]) * w10 + bflo(c11[j]) * w11;
            float hi = bfhi(c00[j]) * w00 + bfhi(c01[j]) * w01 +
                       bfhi(c10[j]) * w10 + bfhi(c11[j]) * w11;
            pk[j] = (unsigned int)f2bf(lo) | ((unsigned int)f2bf(hi) << 16);
        }
        int slot = q ^ (spx & 7);
        *reinterpret_cast<uint4*>(Ab[buf] + spx * 128 + slot * 16) =
            *reinterpret_cast<const uint4*>(pk);
    };

    auto stageB = [&](int buf, int kt) {
        #pragma unroll
        for (int s = 0; s < 2; ++s) {
            int r = s * 64 + w * 8 + (lane >> 3);
            int ch = (lane & 7) ^ (r & 7);
            gload_lds16(&WB[(size_t)r * KP + kt * 64 + ch * 8],
                        Bb[buf] + (s * 64 + w * 8) * 128);
        }
    };

    auto mfma_tile = [&](int c) {
        #pragma unroll
        for (int ks = 0; ks < 2; ++ks) {
            bf16x8 a[2], bfr[2];
            #pragma unroll
            for (int mi = 0; mi < 2; ++mi) {
                int r = mh * 32 + mi * 16 + fr;
                a[mi] = *reinterpret_cast<const bf16x8*>(
                    Ab[c] + r * 128 + (((ks * 4 + fq) ^ (r & 7)) << 4));
            }
            #pragma unroll
            for (int ni = 0; ni < 2; ++ni) {
                int r = nq * 32 + ni * 16 + fr;
                bfr[ni] = *reinterpret_cast<const bf16x8*>(
                    Bb[c] + r * 128 + (((ks * 4 + fq) ^ (r & 7)) << 4));
            }
            __builtin_amdgcn_s_setprio(1);
            #pragma unroll
            for (int mi = 0; mi < 2; ++mi)
                #pragma unroll
                for (int ni = 0; ni < 2; ++ni)
                    acc[mi][ni] = __builtin_amdgcn_mfma_f32_16x16x32_bf16(
                        a[mi], bfr[ni], acc[mi][ni], 0, 0, 0);
            __builtin_amdgcn_s_setprio(0);
        }
    };

    issue_pg(0);
    asm volatile("s_waitcnt vmcnt(0)" ::: "memory");
    fdy = bf2f(rdy); fdx = bf2f(rdx); fmv = bf2f(rmv);
    issue_gather(0);
    asm volatile("" ::: "memory");
    stageB(0, 0);
    asm volatile("" ::: "memory");
    issue_pg(1);
    asm volatile("s_waitcnt vmcnt(5)" ::: "memory");
    combine_write(0);
    asm volatile("s_waitcnt vmcnt(0)" ::: "memory");
    fdy = bf2f(rdy); fdx = bf2f(rdx); fmv = bf2f(rmv);
    asm volatile("s_waitcnt lgkmcnt(0)" ::: "memory");
    __builtin_amdgcn_s_barrier();
    asm volatile("" ::: "memory");

    int cur = 0;
    for (int kt = 0; kt < 16; ++kt) {
        if (kt < 15) {
            issue_gather(kt + 1);
            asm volatile("" ::: "memory");
            stageB(cur ^ 1, kt + 1);
            asm volatile("" ::: "memory");
            issue_pg(min(kt + 2, 15));
            asm volatile("" ::: "memory");
        }
        mfma_tile(cur);
        if (kt < 15) {
            asm volatile("s_waitcnt vmcnt(5)" ::: "memory");
            combine_write(cur ^ 1);
            asm volatile("s_waitcnt vmcnt(0)" ::: "memory");
            fdy = bf2f(rdy); fdx = bf2f(rdx); fmv = bf2f(rmv);
            asm volatile("s_waitcnt lgkmcnt(0)" ::: "memory");
            __builtin_amdgcn_s_barrier();
            asm volatile("" ::: "memory");
            cur ^= 1;
        }
    }

    #pragma unroll
    for (int ni = 0; ni < 2; ++ni) {
        int oc = nq * 32 + ni * 16 + fr;
        if (oc >= On) continue;
        float bv = bias[oc];
        #pragma unroll
        for (int mi = 0; mi < 2; ++mi) {
            int hwo = hw0 + mh * 32 + mi * 16 + fq * 4;
            float4 o;
            o.x = acc[mi][ni][0] + bv;
            o.y = acc[mi][ni][1] + bv;
            o.z = acc[mi][ni][2] + bv;
            o.w = acc[mi][ni][3] + bv;
            *reinterpret_cast<float4*>(
                &out[((size_t)(b * On + oc)) * HW + hwo]) = o;
        }
    }
}

// ---------------------------------------------------------------------------
extern "C" void kernel_launch(void* const* d_in, const int* in_sizes, int n_in,
                              void* d_out, int out_size, void* d_ws, size_t ws_size,
                              hipStream_t stream) {
    const float* x    = (const float*)d_in[0];
    const float* pgw  = (const float*)d_in[1];
    const float* pgb  = (const float*)d_in[2];
    const float* w    = (const float*)d_in[3];
    const float* bias = (const float*)d_in[4];
    float* out = (float*)d_out;

    char* wsb = (char*)d_ws;
    unsigned short* pgBF = (unsigned short*)wsb;                 // 24.77 MB
    size_t off = (size_t)PGC * Bn * HW * 2;
    unsigned short* B2   = (unsigned short*)(wsb + off);         // 0.79 MB
    off += (size_t)NP * KP * 2;
    unsigned short* WB   = (unsigned short*)(wsb + off);         // 0.26 MB
    off += (size_t)128 * KP * 2;
    unsigned short* XTGa = (unsigned short*)(wsb + off);         // 8.93 MB
    unsigned short* XTG  = XTGa + (size_t)XGUARD * 8;            // guarded base

    // prep: zero XTG + build B2 (dense) + WB
    {
        int tot = ZN + B2N + WBN;
        prep_kernel<<<(tot + 255) / 256, 256, 0, stream>>>(pgw, w, XTGa, B2, WB);
    }
    // transpose x -> XTG (group-planar NHWC bf16, 66x66 halo)
    xpose_kernel<<<dim3(Hn, Bn), 256, 0, stream>>>(x, XTG);

    // pg conv v10: A direct from L2 regs, B via LDS
    pg_shift_kernel<<<dim3(PG_MT, NP / 128), 512, 0, stream>>>(
        XTG, B2, pgb, pgBF);

    // fused deformable sampling + main GEMM (64-px blocks)
    fused_kernel<<<dim3(512), 512, 0, stream>>>(XTG, pgBF, WB, bias, out);
}